// Round 1
// baseline (314.340 us; speedup 1.0000x reference)
//
#include <hip/hip_runtime.h>

#define D_DIM 256
#define H_DIM 128

typedef __attribute__((ext_vector_type(8))) short bf16x8;
typedef __attribute__((ext_vector_type(4))) float f32x4;

__device__ __forceinline__ unsigned short f32_to_bf16(float f) {
  unsigned int u = __float_as_uint(f);
  u += 0x7FFFu + ((u >> 16) & 1u);          // round-to-nearest-even
  return (unsigned short)(u >> 16);
}
__device__ __forceinline__ float bf16_to_f32(unsigned short h) {
  return __uint_as_float(((unsigned int)h) << 16);
}

union Frag { unsigned short u[8]; bf16x8 v; };

__device__ __forceinline__ void make_hilo(const float* vals, bf16x8& hi, bf16x8& lo) {
  Frag H, L;
#pragma unroll
  for (int j = 0; j < 8; ++j) {
    unsigned short h = f32_to_bf16(vals[j]);
    H.u[j] = h;
    L.u[j] = f32_to_bf16(vals[j] - bf16_to_f32(h));
  }
  hi = H.v; lo = L.v;
}

__device__ __forceinline__ float tanh_fast(float x) {
  float e = __expf(2.0f * x);
  return 1.0f - 2.0f / (e + 1.0f);
}

// ---------------------------------------------------------------------------
// K1: logits[i] = tanh(x[i]@W1 + b1) @ W2   (b2 omitted -- cancels in softmax)
// Wave tile: 32 nodes (2 x 16). A = x (bf16 hi+lo split), B = W1 (bf16 hi, LDS).
// mfma_f32_16x16x32_bf16: A lane l -> row=l&15, k=(l>>4)*8+j
//                         B lane l -> col=l&15, k=(l>>4)*8+j
//                         D lane l -> col=l&15, row=(l>>4)*4+r   [m89/m91]
// ---------------------------------------------------------------------------
__global__ __launch_bounds__(256, 2)
void logits_kernel(const float* __restrict__ x, const float* __restrict__ W1,
                   const float* __restrict__ b1, const float* __restrict__ W2,
                   float* __restrict__ logits, int N, int nChunks)
{
  // W1 bf16 swizzled: elem (k,n) at [((k>>3)*H + n)*8 + (k&7)] -> frag reads are
  // contiguous 16B ds_read_b128 per lane.
  __shared__ unsigned short w1s[D_DIM * H_DIM]; // 64 KB
  const int tid = threadIdx.x;

  for (int idx4 = tid * 4; idx4 < D_DIM * H_DIM; idx4 += 256 * 4) {
    int k = idx4 >> 7;        // row of W1 (H=128 per row)
    int n = idx4 & 127;
    float4 w = *reinterpret_cast<const float4*>(W1 + idx4);
    int base = ((k >> 3) * H_DIM) * 8 + (k & 7);
    w1s[base + (n + 0) * 8] = f32_to_bf16(w.x);
    w1s[base + (n + 1) * 8] = f32_to_bf16(w.y);
    w1s[base + (n + 2) * 8] = f32_to_bf16(w.z);
    w1s[base + (n + 3) * 8] = f32_to_bf16(w.w);
  }

  const int lane = tid & 63;
  const int wave = tid >> 6;
  const int c = lane & 15;   // col within 16 (n / row-within-16 for A)
  const int q = lane >> 4;   // k-group 0..3

  float b1c[8], w2c[8];
#pragma unroll
  for (int t = 0; t < 8; ++t) {
    b1c[t] = b1[t * 16 + c];
    w2c[t] = W2[t * 16 + c];
  }
  __syncthreads();

  for (int ch = blockIdx.x; ch < nChunks; ch += gridDim.x) {
    int nodeBase = ch * 128 + wave * 32;
    if (nodeBase >= N) continue;
    int r0c = min(nodeBase + c, N - 1);       // clamped load rows
    int r1c = min(nodeBase + 16 + c, N - 1);

    f32x4 acc[2][8];
#pragma unroll
    for (int m = 0; m < 2; ++m)
#pragma unroll
      for (int t = 0; t < 8; ++t) acc[m][t] = (f32x4){0.f, 0.f, 0.f, 0.f};

#pragma unroll
    for (int kt = 0; kt < 8; ++kt) {
      int k0 = kt * 32 + q * 8;
      float4 a0 = *reinterpret_cast<const float4*>(x + (size_t)r0c * D_DIM + k0);
      float4 a1 = *reinterpret_cast<const float4*>(x + (size_t)r0c * D_DIM + k0 + 4);
      float4 b0 = *reinterpret_cast<const float4*>(x + (size_t)r1c * D_DIM + k0);
      float4 b4 = *reinterpret_cast<const float4*>(x + (size_t)r1c * D_DIM + k0 + 4);
      float va[8] = {a0.x, a0.y, a0.z, a0.w, a1.x, a1.y, a1.z, a1.w};
      float vb[8] = {b0.x, b0.y, b0.z, b0.w, b4.x, b4.y, b4.z, b4.w};
      bf16x8 ah, al, bh, bl;
      make_hilo(va, ah, al);
      make_hilo(vb, bh, bl);

#pragma unroll
      for (int nt = 0; nt < 8; ++nt) {
        bf16x8 bf = *reinterpret_cast<const bf16x8*>(
            &w1s[(kt * 4 + q) * 1024 + (nt * 16 + c) * 8]);
        acc[0][nt] = __builtin_amdgcn_mfma_f32_16x16x32_bf16(ah, bf, acc[0][nt], 0, 0, 0);
        acc[0][nt] = __builtin_amdgcn_mfma_f32_16x16x32_bf16(al, bf, acc[0][nt], 0, 0, 0);
        acc[1][nt] = __builtin_amdgcn_mfma_f32_16x16x32_bf16(bh, bf, acc[1][nt], 0, 0, 0);
        acc[1][nt] = __builtin_amdgcn_mfma_f32_16x16x32_bf16(bl, bf, acc[1][nt], 0, 0, 0);
      }
    }

    // epilogue: logit_row = sum_cols tanh(h)*W2[col]; reduce over the 16 col-lanes
#pragma unroll
    for (int m = 0; m < 2; ++m) {
      float lg[4] = {0.f, 0.f, 0.f, 0.f};
#pragma unroll
      for (int nt = 0; nt < 8; ++nt) {
#pragma unroll
        for (int r = 0; r < 4; ++r) {
          float h = acc[m][nt][r] + b1c[nt];
          lg[r] += tanh_fast(h) * w2c[nt];
        }
      }
#pragma unroll
      for (int r = 0; r < 4; ++r) {
        float v = lg[r];
#pragma unroll
        for (int o = 1; o < 16; o <<= 1) v += __shfl_xor(v, o, 64);
        int row = nodeBase + m * 16 + q * 4 + r;
        if (c == 0 && row < N) logits[row] = v;
      }
    }
  }
}

// ---------------------------------------------------------------------------
// K2: segment start offsets via binary search (batch is sorted).
// Runtime int32/int64 detection: setup guarantees batch[N-1] == G-1.
// If storage is int64 (N even -> slot N-1 is a high word) that slot reads 0.
// ---------------------------------------------------------------------------
__global__ void offsets_kernel(const void* __restrict__ batch, int* __restrict__ start,
                               int N, int G)
{
  int g = blockIdx.x * blockDim.x + threadIdx.x;
  if (g > G) return;
  const int* b32 = (const int*)batch;
  bool is64 = (b32[N - 1] != G - 1);
  int lo = 0, hi = N;
  while (lo < hi) {
    int mid = (lo + hi) >> 1;
    long long v = is64 ? ((const long long*)batch)[mid] : (long long)b32[mid];
    if (v < (long long)g) lo = mid + 1; else hi = mid;
  }
  start[g] = lo;
}

// ---------------------------------------------------------------------------
// K3: per-graph softmax + weighted pool. Block per graph; thread = output dim.
// ---------------------------------------------------------------------------
__global__ __launch_bounds__(256)
void pool_kernel(const float* __restrict__ x, const float* __restrict__ logits,
                 const int* __restrict__ start, float* __restrict__ out, int N)
{
  const int g = blockIdx.x;
  const int tid = threadIdx.x;
  const int s = start[g], e = start[g + 1];
  if (s >= e) { out[(size_t)g * D_DIM + tid] = 0.0f; return; }

  const int CAP = 4096;
  __shared__ float red[4];
  __shared__ float ecache[CAP];   // 16 KB; graphs avg ~122 nodes, always fits
  const int lane = tid & 63, wid = tid >> 6;

  // ---- max ----
  float mx = -3.4e38f;
  for (int i = s + tid; i < e; i += 256) mx = fmaxf(mx, logits[i]);
#pragma unroll
  for (int o = 1; o < 64; o <<= 1) mx = fmaxf(mx, __shfl_xor(mx, o, 64));
  if (lane == 0) red[wid] = mx;
  __syncthreads();
  mx = fmaxf(fmaxf(red[0], red[1]), fmaxf(red[2], red[3]));
  __syncthreads();

  // ---- sum of exp (cache e_i) ----
  float sm = 0.0f;
  for (int i = s + tid; i < e; i += 256) {
    float ev = __expf(logits[i] - mx);
    int j = i - s;
    if (j < CAP) ecache[j] = ev;
    sm += ev;
  }
#pragma unroll
  for (int o = 1; o < 64; o <<= 1) sm += __shfl_xor(sm, o, 64);
  if (lane == 0) red[wid] = sm;
  __syncthreads();                 // also publishes ecache
  float inv = 1.0f / (red[0] + red[1] + red[2] + red[3]);

  // ---- weighted pool: thread tid owns dim tid (perfectly coalesced) ----
  float acc = 0.0f;
  const float* xp = x + (size_t)s * D_DIM + tid;
  for (int i = s; i < e; ++i) {
    int j = i - s;
    float w = (j < CAP ? ecache[j] : __expf(logits[i] - mx)) * inv;
    acc = fmaf(w, xp[(size_t)j * D_DIM], acc);
  }
  out[(size_t)g * D_DIM + tid] = acc;
}

// ---------------------------------------------------------------------------
extern "C" void kernel_launch(void* const* d_in, const int* in_sizes, int n_in,
                              void* d_out, int out_size, void* d_ws, size_t ws_size,
                              hipStream_t stream)
{
  const float* x     = (const float*)d_in[0];
  const void*  batch = d_in[1];
  const float* W1    = (const float*)d_in[2];
  const float* b1    = (const float*)d_in[3];
  const float* W2    = (const float*)d_in[4];
  // d_in[5] = b2: cancels exactly in the segment softmax -> unused.

  const int N = in_sizes[0] / D_DIM;     // 500000
  const int G = out_size / D_DIM;        // 4096

  float* logits = (float*)d_ws;
  int*   startA = (int*)((char*)d_ws + (((size_t)N * 4 + 255) / 256) * 256);
  float* out    = (float*)d_out;

  int nChunks = (N + 127) / 128;
  logits_kernel<<<512, 256, 0, stream>>>(x, W1, b1, W2, logits, N, nChunks);
  offsets_kernel<<<(G + 1 + 255) / 256, 256, 0, stream>>>(batch, startA, N, G);
  pool_kernel<<<G, 256, 0, stream>>>(x, logits, startA, out, N);
}

// Round 2
// 296.899 us; speedup vs baseline: 1.0587x; 1.0587x over previous
//
#include <hip/hip_runtime.h>
#include <math.h>

#define D_DIM 256
#define H_DIM 128
#define TILE  32
#define XPAD  260   // 256 + 4 f32 pad -> conflict-free MFMA-frag & dim-column reads

typedef __attribute__((ext_vector_type(8))) short bf16x8;
typedef __attribute__((ext_vector_type(4))) float f32x4;

__device__ __forceinline__ unsigned short f32_to_bf16(float f) {
  unsigned int u = __float_as_uint(f);
  u += 0x7FFFu + ((u >> 16) & 1u);          // RTNE
  return (unsigned short)(u >> 16);
}
__device__ __forceinline__ float bf16_to_f32(unsigned short h) {
  return __uint_as_float(((unsigned int)h) << 16);
}

union Frag8 { unsigned short u[8]; bf16x8 v; };

// split 8 f32 (two float4) into bf16 hi + lo fragments
__device__ __forceinline__ void make_hilo(float4 a, float4 b, bf16x8& hi, bf16x8& lo) {
  Frag8 H, L;
  float f[8] = {a.x, a.y, a.z, a.w, b.x, b.y, b.z, b.w};
#pragma unroll
  for (int j = 0; j < 8; ++j) {
    unsigned short h = f32_to_bf16(f[j]);
    H.u[j] = h;
    L.u[j] = f32_to_bf16(f[j] - bf16_to_f32(h));
  }
  hi = H.v; lo = L.v;
}

__device__ __forceinline__ float tanh_fast(float x) {
  float e = __expf(2.0f * x);
  return 1.0f - 2.0f / (e + 1.0f);
}

// ---------------------------------------------------------------------------
// Setup: pre-swizzle W1 (f32 [256][128]) into per-lane bf16 B-fragments.
// Fragment f = kt*2+nt of thread t (lane l = t&63, wave w = t>>6):
//   elem j = W1[kt*32 + (l>>4)*8 + j][w*32 + nt*16 + (l&15)]
// Layout ws[(f*256 + t)] as bf16x8 -> main-kernel loads are fully coalesced.
// ---------------------------------------------------------------------------
__global__ void setup_w1_kernel(const float* __restrict__ W1,
                                unsigned short* __restrict__ wfrag)
{
  const int t = threadIdx.x;
  const int l = t & 63, w = t >> 6;
  const int q = l >> 4, c = l & 15;
#pragma unroll
  for (int kt = 0; kt < 8; ++kt)
#pragma unroll
    for (int nt = 0; nt < 2; ++nt) {
      int f = kt * 2 + nt;
      int col = w * 32 + nt * 16 + c;
#pragma unroll
      for (int j = 0; j < 8; ++j) {
        int k = kt * 32 + q * 8 + j;
        wfrag[((size_t)f * 256 + t) * 8 + j] = f32_to_bf16(W1[k * H_DIM + col]);
      }
    }
}

// ---------------------------------------------------------------------------
// Segment start offsets via binary search (batch sorted; int32/int64 runtime
// detect via sentinel batch[N-1] == G-1).
// ---------------------------------------------------------------------------
__global__ void offsets_kernel(const void* __restrict__ batch, int* __restrict__ start,
                               int N, int G)
{
  int g = blockIdx.x * blockDim.x + threadIdx.x;
  if (g > G) return;
  const int* b32 = (const int*)batch;
  bool is64 = (b32[N - 1] != G - 1);
  int lo = 0, hi = N;
  while (lo < hi) {
    int mid = (lo + hi) >> 1;
    long long v = is64 ? ((const long long*)batch)[mid] : (long long)b32[mid];
    if (v < (long long)g) lo = mid + 1; else hi = mid;
  }
  start[g] = lo;
}

// ---------------------------------------------------------------------------
// Fused: block per graph. Per 32-node tile: stage x->LDS f32, MFMA logits
// (wave owns 32 H-cols, W1 frags in regs, x hi/lo split), tanh+W2 reduce,
// online-softmax rescale + weighted accumulate (thread = output dim).
// x is read from HBM exactly once.
// ---------------------------------------------------------------------------
__global__ __launch_bounds__(256, 3)
void fused_kernel(const float* __restrict__ x, const unsigned short* __restrict__ wfrag,
                  const float* __restrict__ b1, const float* __restrict__ W2,
                  const int* __restrict__ start, float* __restrict__ out, int N)
{
  __shared__ float xt[TILE][XPAD];   // 33.3 KB
  __shared__ float part[4][TILE];    // per-wave logit partials

  const int g = blockIdx.x;
  const int tid = threadIdx.x;
  const int s = start[g], e = start[g + 1];
  if (s >= e) { out[(size_t)g * D_DIM + tid] = 0.0f; return; }
  const int len = e - s;

  const int lane = tid & 63, w = tid >> 6;
  const int q = lane >> 4, c = lane & 15;

  // W1 B-fragments: 16 x bf16x8 = 64 VGPR, coalesced loads (L2-resident)
  bf16x8 wf[8][2];
#pragma unroll
  for (int kt = 0; kt < 8; ++kt)
#pragma unroll
    for (int nt = 0; nt < 2; ++nt)
      wf[kt][nt] = ((const bf16x8*)wfrag)[(kt * 2 + nt) * 256 + tid];

  float b1c[2], w2c[2];
#pragma unroll
  for (int nt = 0; nt < 2; ++nt) {
    int col = w * 32 + nt * 16 + c;
    b1c[nt] = b1[col];
    w2c[nt] = W2[col];
  }

  float m_run = -INFINITY, Z = 0.0f, accd = 0.0f;

  const int nT = (len + TILE - 1) / TILE;
  for (int ti = 0; ti < nT; ++ti) {
    const int t0 = ti * TILE;

    // ---- stage x tile (coalesced: wave reads contiguous 1 KB per inst) ----
#pragma unroll
    for (int r = 0; r < 8; ++r) {
      int idx = tid + 256 * r;
      int row = idx >> 6, c4 = (idx & 63) * 4;
      int gr = min(s + t0 + row, N - 1);          // rows past e: weight-0 later
      float4 v = *reinterpret_cast<const float4*>(x + (size_t)gr * D_DIM + c4);
      *reinterpret_cast<float4*>(&xt[row][c4]) = v;
    }
    __syncthreads();

    // ---- MFMA: h-tile = x_tile @ W1[:, wave cols] (hi/lo split) ----
    f32x4 acc[2][2];
#pragma unroll
    for (int m = 0; m < 2; ++m)
#pragma unroll
      for (int nt = 0; nt < 2; ++nt) acc[m][nt] = (f32x4){0.f, 0.f, 0.f, 0.f};

#pragma unroll
    for (int kt = 0; kt < 8; ++kt) {
      bf16x8 ah0, al0, ah1, al1;
      {
        const float* p = &xt[c][kt * 32 + q * 8];
        make_hilo(*reinterpret_cast<const float4*>(p),
                  *reinterpret_cast<const float4*>(p + 4), ah0, al0);
        const float* p1 = &xt[16 + c][kt * 32 + q * 8];
        make_hilo(*reinterpret_cast<const float4*>(p1),
                  *reinterpret_cast<const float4*>(p1 + 4), ah1, al1);
      }
#pragma unroll
      for (int nt = 0; nt < 2; ++nt) {
        acc[0][nt] = __builtin_amdgcn_mfma_f32_16x16x32_bf16(ah0, wf[kt][nt], acc[0][nt], 0, 0, 0);
        acc[0][nt] = __builtin_amdgcn_mfma_f32_16x16x32_bf16(al0, wf[kt][nt], acc[0][nt], 0, 0, 0);
        acc[1][nt] = __builtin_amdgcn_mfma_f32_16x16x32_bf16(ah1, wf[kt][nt], acc[1][nt], 0, 0, 0);
        acc[1][nt] = __builtin_amdgcn_mfma_f32_16x16x32_bf16(al1, wf[kt][nt], acc[1][nt], 0, 0, 0);
      }
    }

    // ---- tanh + W2 dot; reduce across the 16 col-lanes ----
#pragma unroll
    for (int m = 0; m < 2; ++m)
#pragma unroll
      for (int r = 0; r < 4; ++r) {
        float v = tanh_fast(acc[m][0][r] + b1c[0]) * w2c[0]
                + tanh_fast(acc[m][1][r] + b1c[1]) * w2c[1];
#pragma unroll
        for (int o = 1; o < 16; o <<= 1) v += __shfl_xor(v, o, 64);
        if (c == 0) part[w][m * 16 + q * 4 + r] = v;
      }
    __syncthreads();

    // ---- online softmax update + weighted pool (thread = dim) ----
    const int iend = min(TILE, len - t0);
    float tmax = -INFINITY;
    for (int i = 0; i < iend; ++i) {
      float li = part[0][i] + part[1][i] + part[2][i] + part[3][i];
      tmax = fmaxf(tmax, li);
    }
    float m_new = fmaxf(m_run, tmax);
    float scale = __expf(m_run - m_new);   // exp(-inf - finite) = 0 on first tile
    Z *= scale;
    accd *= scale;
    for (int i = 0; i < iend; ++i) {
      float li = part[0][i] + part[1][i] + part[2][i] + part[3][i];
      float ei = __expf(li - m_new);
      Z += ei;
      accd = fmaf(ei, xt[i][tid], accd);
    }
    m_run = m_new;
    __syncthreads();   // xt/part reuse next tile
  }

  out[(size_t)g * D_DIM + tid] = accd / Z;
}

// ---------------------------------------------------------------------------
extern "C" void kernel_launch(void* const* d_in, const int* in_sizes, int n_in,
                              void* d_out, int out_size, void* d_ws, size_t ws_size,
                              hipStream_t stream)
{
  const float* x     = (const float*)d_in[0];
  const void*  batch = d_in[1];
  const float* W1    = (const float*)d_in[2];
  const float* b1    = (const float*)d_in[3];
  const float* W2    = (const float*)d_in[4];
  // d_in[5] = b2: cancels exactly in the segment softmax -> unused.

  const int N = in_sizes[0] / D_DIM;     // 500000
  const int G = out_size / D_DIM;        // 4096

  unsigned short* wfrag = (unsigned short*)d_ws;              // 16*256*8 bf16 = 64 KB
  int* startA = (int*)((char*)d_ws + 16 * 256 * 8 * sizeof(unsigned short));
  float* out = (float*)d_out;

  setup_w1_kernel<<<1, 256, 0, stream>>>(W1, wfrag);
  offsets_kernel<<<(G + 1 + 255) / 256, 256, 0, stream>>>(batch, startA, N, G);
  fused_kernel<<<G, 256, 0, stream>>>(x, wfrag, b1, W2, startA, out, N);
}

// Round 3
// 200.579 us; speedup vs baseline: 1.5672x; 1.4802x over previous
//
#include <hip/hip_runtime.h>
#include <math.h>

#define D_DIM 256
#define H_DIM 128
#define TILE  32
#define HPAD  264   // shorts per LDS row: 256 + 8 -> row stride 528 B (4-bank step, 2-way max)

typedef __attribute__((ext_vector_type(8))) short bf16x8;
typedef __attribute__((ext_vector_type(4))) float f32x4;

__device__ __forceinline__ unsigned short f32_to_bf16(float f) {
  unsigned int u = __float_as_uint(f);
  u += 0x7FFFu + ((u >> 16) & 1u);          // RTNE (setup kernel only)
  return (unsigned short)(u >> 16);
}

// hi = truncate-to-bf16 (cheap: AND), residual r returned for the lo term.
// x ~= hi + lo to 2^-14 rel, independent of hi's rounding mode.
__device__ __forceinline__ unsigned int pack_hi2(float f0, float f1, float& r0, float& r1) {
  unsigned int u0 = __float_as_uint(f0) & 0xFFFF0000u;
  unsigned int u1 = __float_as_uint(f1) & 0xFFFF0000u;
  r0 = f0 - __uint_as_float(u0);
  r1 = f1 - __uint_as_float(u1);
  return (u0 >> 16) | u1;
}
__device__ __forceinline__ unsigned int pack_lo2(float r0, float r1) {
  return (__float_as_uint(r0) >> 16) | (__float_as_uint(r1) & 0xFFFF0000u);
}

__device__ __forceinline__ float tanh_fast(float x) {
  float e = __expf(2.0f * x);
  return 1.0f - 2.0f / (e + 1.0f);
}

// ---------------------------------------------------------------------------
// Setup: pre-swizzle W1 (f32 [256][128]) into per-lane bf16 B-fragments.
// Fragment f = kt*2+nt of thread t (lane l=t&63, wave w=t>>6):
//   elem j = W1[kt*32 + (l>>4)*8 + j][w*32 + nt*16 + (l&15)]
// ---------------------------------------------------------------------------
__global__ void setup_w1_kernel(const float* __restrict__ W1,
                                unsigned short* __restrict__ wfrag)
{
  const int t = threadIdx.x;
  const int l = t & 63, w = t >> 6;
  const int q = l >> 4, c = l & 15;
#pragma unroll
  for (int kt = 0; kt < 8; ++kt)
#pragma unroll
    for (int nt = 0; nt < 2; ++nt) {
      int f = kt * 2 + nt;
      int col = w * 32 + nt * 16 + c;
#pragma unroll
      for (int j = 0; j < 8; ++j) {
        int k = kt * 32 + q * 8 + j;
        wfrag[((size_t)f * 256 + t) * 8 + j] = f32_to_bf16(W1[k * H_DIM + col]);
      }
    }
}

// ---------------------------------------------------------------------------
// Segment start offsets (batch sorted; int32/int64 runtime detect).
// ---------------------------------------------------------------------------
__global__ void offsets_kernel(const void* __restrict__ batch, int* __restrict__ start,
                               int N, int G)
{
  int g = blockIdx.x * blockDim.x + threadIdx.x;
  if (g > G) return;
  const int* b32 = (const int*)batch;
  bool is64 = (b32[N - 1] != G - 1);
  int lo = 0, hi = N;
  while (lo < hi) {
    int mid = (lo + hi) >> 1;
    long long v = is64 ? ((const long long*)batch)[mid] : (long long)b32[mid];
    if (v < (long long)g) lo = mid + 1; else hi = mid;
  }
  start[g] = lo;
}

// ---------------------------------------------------------------------------
// Fused single-pass: block per graph. Per 32-node tile:
//  1) stage x -> LDS as bf16 hi/lo (convert ONCE per element),
//  2) MFMA logits (frags are raw ds_read_b128; W1 frags live in 64 VGPR),
//  3) tanh + W2 dot + 16-lane reduce -> part[w][i],
//  4) every wave: li/e_i in-lane, shfl-broadcast, online rescale + pool
//     (x reconstructed as hi+lo, exact to 2^-14).
// x is read from HBM exactly once.
// ---------------------------------------------------------------------------
__global__ __launch_bounds__(256, 4)
void fused_kernel(const float* __restrict__ x, const unsigned short* __restrict__ wfrag,
                  const float* __restrict__ b1, const float* __restrict__ W2,
                  const int* __restrict__ start, float* __restrict__ out, int N)
{
  __shared__ unsigned short xhi[TILE][HPAD];  // 16.9 KB
  __shared__ unsigned short xlo[TILE][HPAD];  // 16.9 KB
  __shared__ float part[4][TILE];

  const int g = blockIdx.x;
  const int tid = threadIdx.x;
  const int s = start[g], e = start[g + 1];
  if (s >= e) { out[(size_t)g * D_DIM + tid] = 0.0f; return; }
  const int len = e - s;

  const int lane = tid & 63, w = tid >> 6;
  const int q = lane >> 4, c = lane & 15;

  // W1 B-fragments: 16 x bf16x8 = 64 VGPR (coalesced, L2-resident)
  bf16x8 wf[8][2];
#pragma unroll
  for (int kt = 0; kt < 8; ++kt)
#pragma unroll
    for (int nt = 0; nt < 2; ++nt)
      wf[kt][nt] = ((const bf16x8*)wfrag)[(kt * 2 + nt) * 256 + tid];

  float b1c[2], w2c[2];
#pragma unroll
  for (int nt = 0; nt < 2; ++nt) {
    int col = w * 32 + nt * 16 + c;
    b1c[nt] = b1[col];
    w2c[nt] = W2[col];
  }

  float m_run = -INFINITY, Z = 0.0f, accd = 0.0f;

  const int nT = (len + TILE - 1) / TILE;
  for (int ti = 0; ti < nT; ++ti) {
    const int t0 = ti * TILE;
    const int iend = min(TILE, len - t0);

    // ---- stage: 8-elem chunk per thread per iter; hi/lo split once ----
#pragma unroll
    for (int it = 0; it < 4; ++it) {
      int id = tid + 256 * it;
      int row = id >> 5, col8 = (id & 31) * 8;
      int gr = min(s + t0 + row, N - 1);          // pad rows get weight 0 later
      const float4* gp = reinterpret_cast<const float4*>(x + (size_t)gr * D_DIM + col8);
      float4 A = gp[0], B = gp[1];
      float r0, r1, r2, r3, r4, r5, r6, r7;
      uint4 H, L;
      H.x = pack_hi2(A.x, A.y, r0, r1);
      H.y = pack_hi2(A.z, A.w, r2, r3);
      H.z = pack_hi2(B.x, B.y, r4, r5);
      H.w = pack_hi2(B.z, B.w, r6, r7);
      L.x = pack_lo2(r0, r1);
      L.y = pack_lo2(r2, r3);
      L.z = pack_lo2(r4, r5);
      L.w = pack_lo2(r6, r7);
      *reinterpret_cast<uint4*>(&xhi[row][col8]) = H;
      *reinterpret_cast<uint4*>(&xlo[row][col8]) = L;
    }
    __syncthreads();

    // ---- MFMA: h-tile = x_tile @ W1[:, wave's 32 cols] (hi + lo terms) ----
    f32x4 acc[2][2];
#pragma unroll
    for (int m = 0; m < 2; ++m)
#pragma unroll
      for (int nt = 0; nt < 2; ++nt) acc[m][nt] = (f32x4){0.f, 0.f, 0.f, 0.f};

#pragma unroll
    for (int kt = 0; kt < 8; ++kt) {
      const int koff = kt * 32 + q * 8;
      bf16x8 ah0 = *reinterpret_cast<const bf16x8*>(&xhi[c][koff]);
      bf16x8 al0 = *reinterpret_cast<const bf16x8*>(&xlo[c][koff]);
      bf16x8 ah1 = *reinterpret_cast<const bf16x8*>(&xhi[16 + c][koff]);
      bf16x8 al1 = *reinterpret_cast<const bf16x8*>(&xlo[16 + c][koff]);
#pragma unroll
      for (int nt = 0; nt < 2; ++nt) {
        acc[0][nt] = __builtin_amdgcn_mfma_f32_16x16x32_bf16(ah0, wf[kt][nt], acc[0][nt], 0, 0, 0);
        acc[0][nt] = __builtin_amdgcn_mfma_f32_16x16x32_bf16(al0, wf[kt][nt], acc[0][nt], 0, 0, 0);
        acc[1][nt] = __builtin_amdgcn_mfma_f32_16x16x32_bf16(ah1, wf[kt][nt], acc[1][nt], 0, 0, 0);
        acc[1][nt] = __builtin_amdgcn_mfma_f32_16x16x32_bf16(al1, wf[kt][nt], acc[1][nt], 0, 0, 0);
      }
    }

    // ---- tanh + W2 dot; reduce across the 16 col-lanes -> part[w][i] ----
#pragma unroll
    for (int m = 0; m < 2; ++m)
#pragma unroll
      for (int r = 0; r < 4; ++r) {
        float v = tanh_fast(acc[m][0][r] + b1c[0]) * w2c[0]
                + tanh_fast(acc[m][1][r] + b1c[1]) * w2c[1];
#pragma unroll
        for (int o = 1; o < 16; o <<= 1) v += __shfl_xor(v, o, 64);
        if (c == 0) part[w][m * 16 + q * 4 + r] = v;
      }
    __syncthreads();

    // ---- online softmax + pool (every wave independently; lane i owns e_i) ----
    {
      int i = lane & 31;
      float li = (i < iend) ? (part[0][i] + part[1][i] + part[2][i] + part[3][i])
                            : -INFINITY;
      float tmax = li;
#pragma unroll
      for (int o = 1; o < 64; o <<= 1) tmax = fmaxf(tmax, __shfl_xor(tmax, o, 64));
      float m_new = fmaxf(m_run, tmax);
      float ei = __expf(li - m_new);              // 0 for pad rows
      float esum = ei;
#pragma unroll
      for (int o = 1; o < 32; o <<= 1) esum += __shfl_xor(esum, o, 64);
      float scale = __expf(m_run - m_new);        // first tile: exp(-inf)=0
      Z = Z * scale + esum;
      accd *= scale;
      for (int ii = 0; ii < iend; ++ii) {
        float ev = __shfl(ei, ii, 64);            // broadcast e_ii from lane ii
        float xv = __uint_as_float((unsigned int)xhi[ii][tid] << 16)
                 + __uint_as_float((unsigned int)xlo[ii][tid] << 16);
        accd = fmaf(ev, xv, accd);
      }
      m_run = m_new;
    }
    __syncthreads();   // xt/part reuse next tile
  }

  out[(size_t)g * D_DIM + tid] = accd / Z;
}

// ---------------------------------------------------------------------------
extern "C" void kernel_launch(void* const* d_in, const int* in_sizes, int n_in,
                              void* d_out, int out_size, void* d_ws, size_t ws_size,
                              hipStream_t stream)
{
  const float* x     = (const float*)d_in[0];
  const void*  batch = d_in[1];
  const float* W1    = (const float*)d_in[2];
  const float* b1    = (const float*)d_in[3];
  const float* W2    = (const float*)d_in[4];
  // d_in[5] = b2: cancels exactly in the segment softmax -> unused.

  const int N = in_sizes[0] / D_DIM;     // 500000
  const int G = out_size / D_DIM;        // 4096

  unsigned short* wfrag = (unsigned short*)d_ws;              // 16*256*8 bf16 = 64 KB
  int* startA = (int*)((char*)d_ws + 16 * 256 * 8 * sizeof(unsigned short));
  float* out = (float*)d_out;

  setup_w1_kernel<<<1, 256, 0, stream>>>(W1, wfrag);
  offsets_kernel<<<(G + 1 + 255) / 256, 256, 0, stream>>>(batch, startA, N, G);
  fused_kernel<<<G, 256, 0, stream>>>(x, wfrag, b1, W2, startA, out, N);
}